// Round 1
// baseline (317.688 us; speedup 1.0000x reference)
//
#include <hip/hip_runtime.h>
#include <math.h>

// Legendre-KAN: y[n,o] = sum_{i,d} P_d(xn[n,i]) * coeffs[o,i,d] + bias[o]
// GEMM view: A[N x 4096] (on-the-fly Legendre basis, bf16) * B[4096 x 64] (coeffs, bf16)
// MFMA 16x16x32 bf16. A-frag: lane holds A[m=lane&15][k=quad*8+j] -> one x element/lane/K-tile.

typedef __bf16 bf16x8 __attribute__((ext_vector_type(8)));
typedef float f32x4 __attribute__((ext_vector_type(4)));

// ---------------- pass 1a: per-block min/max ----------------
__global__ __launch_bounds__(256) void k_minmax_partial(
    const float4* __restrict__ x4, int n4, float* __restrict__ pmn, float* __restrict__ pmx)
{
  float mn = 3.4e38f, mx = -3.4e38f;
  int stride = gridDim.x * 256;
  for (int i = blockIdx.x * 256 + threadIdx.x; i < n4; i += stride) {
    float4 v = x4[i];
    mn = fminf(mn, fminf(fminf(v.x, v.y), fminf(v.z, v.w)));
    mx = fmaxf(mx, fmaxf(fmaxf(v.x, v.y), fmaxf(v.z, v.w)));
  }
  #pragma unroll
  for (int off = 32; off > 0; off >>= 1) {
    mn = fminf(mn, __shfl_down(mn, off));
    mx = fmaxf(mx, __shfl_down(mx, off));
  }
  __shared__ float smn[4], smx[4];
  int w = threadIdx.x >> 6;
  if ((threadIdx.x & 63) == 0) { smn[w] = mn; smx[w] = mx; }
  __syncthreads();
  if (threadIdx.x == 0) {
    pmn[blockIdx.x] = fminf(fminf(smn[0], smn[1]), fminf(smn[2], smn[3]));
    pmx[blockIdx.x] = fmaxf(fmaxf(smx[0], smx[1]), fmaxf(smx[2], smx[3]));
  }
}

// ---------------- pass 1b: final reduce -> scale/offset ----------------
__global__ __launch_bounds__(256) void k_minmax_final(
    const float* __restrict__ pmn, const float* __restrict__ pmx, int nb, float* __restrict__ so)
{
  float mn = 3.4e38f, mx = -3.4e38f;
  for (int i = threadIdx.x; i < nb; i += 256) {
    mn = fminf(mn, pmn[i]);
    mx = fmaxf(mx, pmx[i]);
  }
  #pragma unroll
  for (int off = 32; off > 0; off >>= 1) {
    mn = fminf(mn, __shfl_down(mn, off));
    mx = fmaxf(mx, __shfl_down(mx, off));
  }
  __shared__ float smn[4], smx[4];
  int w = threadIdx.x >> 6;
  if ((threadIdx.x & 63) == 0) { smn[w] = mn; smx[w] = mx; }
  __syncthreads();
  if (threadIdx.x == 0) {
    mn = fminf(fminf(smn[0], smn[1]), fminf(smn[2], smn[3]));
    mx = fmaxf(fmaxf(smx[0], smx[1]), fmaxf(smx[2], smx[3]));
    float r = mx - mn;
    so[0] = 2.0f / r;               // scale
    so[1] = -2.0f * mn / r - 1.0f;  // offset:  xn = x*s + o
  }
}

// ---------------- prep: coeffs fp32 -> bf16 B-fragment layout ----------------
// ws_B[t = (kt*4+ct)*64 + lane][j] = coeffs[o=ct*16+(lane&15)][i=kt*4+(lane>>4)][d=j]
__global__ __launch_bounds__(256) void k_prepB(const float* __restrict__ coeffs,
                                               bf16x8* __restrict__ Bws)
{
  int t = blockIdx.x * 256 + threadIdx.x;   // [0, 32768)
  int lane = t & 63;
  int tile = t >> 6;                        // kt*4 + ct
  int ct = tile & 3;
  int kt = tile >> 2;
  int i = kt * 4 + (lane >> 4);
  int o = ct * 16 + (lane & 15);
  const float4* cp = (const float4*)(coeffs + ((size_t)o * 512 + i) * 8);
  float4 c0 = cp[0], c1 = cp[1];
  bf16x8 v;
  v[0] = (__bf16)c0.x; v[1] = (__bf16)c0.y; v[2] = (__bf16)c0.z; v[3] = (__bf16)c0.w;
  v[4] = (__bf16)c1.x; v[5] = (__bf16)c1.y; v[6] = (__bf16)c1.z; v[7] = (__bf16)c1.w;
  Bws[t] = v;
}

// ---------------- pass 2: fused basis + MFMA GEMM ----------------
// Block: 64 rows of A (4 waves x 16 rows), all 64 output cols (4 MFMA col-tiles).
template <bool PRE>
__global__ __launch_bounds__(256) void k_main(
    const float* __restrict__ x, const bf16x8* __restrict__ Bws,
    const float* __restrict__ coeffs, const float* __restrict__ bias,
    const float* __restrict__ so, float* __restrict__ y)
{
  const float s = so[0], off = so[1];
  const int lane = threadIdx.x & 63;
  const int w    = threadIdx.x >> 6;
  const int m    = lane & 15;
  const int quad = lane >> 4;
  const int rowA = blockIdx.x * 64 + w * 16 + m;

  const float*  xp = x + (size_t)rowA * 512 + quad;   // x[rowA][4*kt + quad]
  const bf16x8* bp = Bws + lane;

  f32x4 acc0 = {0.f, 0.f, 0.f, 0.f};
  f32x4 acc1 = acc0, acc2 = acc0, acc3 = acc0;

  const float c3a = 5.f / 3.f,  c3b = 2.f / 3.f;
  const float c6a = 11.f / 6.f, c6b = 5.f / 6.f;
  const float c7a = 13.f / 7.f, c7b = 6.f / 7.f;

  #pragma unroll 2
  for (int kt = 0; kt < 128; ++kt) {
    float xv = xp[kt * 4];

    bf16x8 b0, b1, b2, b3;
    if (PRE) {
      const bf16x8* bpk = bp + kt * 256;
      b0 = bpk[0]; b1 = bpk[64]; b2 = bpk[128]; b3 = bpk[192];
    } else {
      int i = kt * 4 + quad;
      #pragma unroll
      for (int ct = 0; ct < 4; ++ct) {
        const float* cp = coeffs + ((size_t)(ct * 16 + m) * 512 + i) * 8;
        bf16x8 bv;
        #pragma unroll
        for (int j = 0; j < 8; ++j) bv[j] = (__bf16)cp[j];
        if (ct == 0) b0 = bv; else if (ct == 1) b1 = bv;
        else if (ct == 2) b2 = bv; else b3 = bv;
      }
    }

    // Legendre basis, fp32 recurrence: P_n = ((2n-1)/n) x P_{n-1} - ((n-1)/n) P_{n-2}
    float xn = fmaf(xv, s, off);
    float p2 = fmaf(1.5f * xn, xn, -0.5f);
    float p3 = fmaf(c3a * xn, p2, -(c3b * xn));
    float p4 = fmaf(1.75f * xn, p3, -(0.75f * p2));
    float p5 = fmaf(1.8f * xn, p4, -(0.8f * p3));
    float p6 = fmaf(c6a * xn, p5, -(c6b * p4));
    float p7 = fmaf(c7a * xn, p6, -(c7b * p5));

    bf16x8 a;
    a[0] = (__bf16)1.0f; a[1] = (__bf16)xn; a[2] = (__bf16)p2; a[3] = (__bf16)p3;
    a[4] = (__bf16)p4;   a[5] = (__bf16)p5; a[6] = (__bf16)p6; a[7] = (__bf16)p7;

    acc0 = __builtin_amdgcn_mfma_f32_16x16x32_bf16(a, b0, acc0, 0, 0, 0);
    acc1 = __builtin_amdgcn_mfma_f32_16x16x32_bf16(a, b1, acc1, 0, 0, 0);
    acc2 = __builtin_amdgcn_mfma_f32_16x16x32_bf16(a, b2, acc2, 0, 0, 0);
    acc3 = __builtin_amdgcn_mfma_f32_16x16x32_bf16(a, b3, acc3, 0, 0, 0);
  }

  // C/D layout: col = lane&15, row = quad*4 + reg
  float b0v = bias[m], b1v = bias[16 + m], b2v = bias[32 + m], b3v = bias[48 + m];
  float* yp = y + ((size_t)(blockIdx.x * 64 + w * 16 + quad * 4)) * 64 + m;
  #pragma unroll
  for (int r = 0; r < 4; ++r) {
    yp[r * 64 +  0] = acc0[r] + b0v;
    yp[r * 64 + 16] = acc1[r] + b1v;
    yp[r * 64 + 32] = acc2[r] + b2v;
    yp[r * 64 + 48] = acc3[r] + b3v;
  }
}

extern "C" void kernel_launch(void* const* d_in, const int* in_sizes, int n_in,
                              void* d_out, int out_size, void* d_ws, size_t ws_size,
                              hipStream_t stream)
{
  const float* x      = (const float*)d_in[0];
  const float* coeffs = (const float*)d_in[1];
  const float* bias   = (const float*)d_in[2];
  float* y = (float*)d_out;

  long nx = (long)in_sizes[0];        // 16*4096*512 = 33,554,432
  int  N  = (int)(nx / 512);          // 65536 rows
  int  n4 = (int)(nx / 4);

  // workspace layout: [0,8): scale/offset floats; [64, 64+8KiB): partials; [16384, +512KiB): B bf16
  float*  so  = (float*)d_ws;
  float*  pmn = (float*)d_ws + 16;
  float*  pmx = pmn + 1024;
  bf16x8* Bws = (bf16x8*)((char*)d_ws + 16384);

  const int MMB = 1024;
  k_minmax_partial<<<MMB, 256, 0, stream>>>((const float4*)x, n4, pmn, pmx);
  k_minmax_final<<<1, 256, 0, stream>>>(pmn, pmx, MMB, so);

  bool pre = ws_size >= (size_t)(16384 + 4096 * 64 * 2);
  if (pre) {
    k_prepB<<<128, 256, 0, stream>>>(coeffs, Bws);
    k_main<true><<<N / 64, 256, 0, stream>>>(x, Bws, coeffs, bias, so, y);
  } else {
    k_main<false><<<N / 64, 256, 0, stream>>>(x, Bws, coeffs, bias, so, y);
  }
}

// Round 2
// 287.546 us; speedup vs baseline: 1.1048x; 1.1048x over previous
//
#include <hip/hip_runtime.h>
#include <math.h>

// Legendre-KAN: y[n,o] = sum_{i,d} P_d(xn[n,i]) * coeffs[o,i,d] + bias[o]
// GEMM view: A[65536 x 4096] (on-the-fly Legendre basis, bf16) * B[4096 x 64] (coeffs bf16).
// MFMA 16x16x32 bf16. Wave = 64 rows x 64 cols (4 row-frags x 4 col-frags, 16 accs)
// -> B L2 traffic amortized 4x vs 16-row waves. x staged via double-buffered LDS.

typedef __bf16 bf16x8 __attribute__((ext_vector_type(8)));
typedef float f32x4 __attribute__((ext_vector_type(4)));

// ---------------- pass 1a: per-block min/max ----------------
__global__ __launch_bounds__(256) void k_minmax_partial(
    const float4* __restrict__ x4, int n4, float* __restrict__ pmn, float* __restrict__ pmx)
{
  float mn = 3.4e38f, mx = -3.4e38f;
  int stride = gridDim.x * 256;
  for (int i = blockIdx.x * 256 + threadIdx.x; i < n4; i += stride) {
    float4 v = x4[i];
    mn = fminf(mn, fminf(fminf(v.x, v.y), fminf(v.z, v.w)));
    mx = fmaxf(mx, fmaxf(fmaxf(v.x, v.y), fmaxf(v.z, v.w)));
  }
  #pragma unroll
  for (int off = 32; off > 0; off >>= 1) {
    mn = fminf(mn, __shfl_down(mn, off));
    mx = fmaxf(mx, __shfl_down(mx, off));
  }
  __shared__ float smn[4], smx[4];
  int w = threadIdx.x >> 6;
  if ((threadIdx.x & 63) == 0) { smn[w] = mn; smx[w] = mx; }
  __syncthreads();
  if (threadIdx.x == 0) {
    pmn[blockIdx.x] = fminf(fminf(smn[0], smn[1]), fminf(smn[2], smn[3]));
    pmx[blockIdx.x] = fmaxf(fmaxf(smx[0], smx[1]), fmaxf(smx[2], smx[3]));
  }
}

// ---------------- pass 1b: final reduce -> scale/offset ----------------
__global__ __launch_bounds__(256) void k_minmax_final(
    const float* __restrict__ pmn, const float* __restrict__ pmx, int nb, float* __restrict__ so)
{
  float mn = 3.4e38f, mx = -3.4e38f;
  for (int i = threadIdx.x; i < nb; i += 256) {
    mn = fminf(mn, pmn[i]);
    mx = fmaxf(mx, pmx[i]);
  }
  #pragma unroll
  for (int off = 32; off > 0; off >>= 1) {
    mn = fminf(mn, __shfl_down(mn, off));
    mx = fmaxf(mx, __shfl_down(mx, off));
  }
  __shared__ float smn[4], smx[4];
  int w = threadIdx.x >> 6;
  if ((threadIdx.x & 63) == 0) { smn[w] = mn; smx[w] = mx; }
  __syncthreads();
  if (threadIdx.x == 0) {
    mn = fminf(fminf(smn[0], smn[1]), fminf(smn[2], smn[3]));
    mx = fmaxf(fmaxf(smx[0], smx[1]), fmaxf(smx[2], smx[3]));
    float r = mx - mn;
    so[0] = 2.0f / r;               // scale
    so[1] = -2.0f * mn / r - 1.0f;  // offset:  xn = x*s + o
  }
}

// ---------------- prep: coeffs fp32 -> bf16 B-fragment layout ----------------
// Bws[t = (kt*4+ct)*64 + lane][j] = coeffs[o=ct*16+(lane&15)][i=kt*4+(lane>>4)][d=j]
__global__ __launch_bounds__(256) void k_prepB(const float* __restrict__ coeffs,
                                               bf16x8* __restrict__ Bws)
{
  int t = blockIdx.x * 256 + threadIdx.x;   // [0, 32768)
  int lane = t & 63;
  int tile = t >> 6;                        // kt*4 + ct
  int ct = tile & 3;
  int kt = tile >> 2;
  int i = kt * 4 + (lane >> 4);
  int o = ct * 16 + (lane & 15);
  const float4* cp = (const float4*)(coeffs + ((size_t)o * 512 + i) * 8);
  float4 c0 = cp[0], c1 = cp[1];
  bf16x8 v;
  v[0] = (__bf16)c0.x; v[1] = (__bf16)c0.y; v[2] = (__bf16)c0.z; v[3] = (__bf16)c0.w;
  v[4] = (__bf16)c1.x; v[5] = (__bf16)c1.y; v[6] = (__bf16)c1.z; v[7] = (__bf16)c1.w;
  Bws[t] = v;
}

// ---------------- pass 2: fused basis + MFMA GEMM ----------------
// Block = 128 threads (2 waves), each wave: 64 rows x 64 cols. Block covers 128 rows.
// x staged in LDS (chunks of 8 K-tiles = 32 cols), double-buffered, pad-36 stride.
#define LSTRIDE 36
__global__ __launch_bounds__(128, 1) void k_main(
    const float* __restrict__ x, const bf16x8* __restrict__ Bws,
    const float* __restrict__ bias, const float* __restrict__ so,
    float* __restrict__ y)
{
  __shared__ float xs[2][128 * LSTRIDE];   // 36 KiB

  const float s = so[0], off = so[1];
  const int t    = threadIdx.x;
  const int lane = t & 63;
  const int w    = t >> 6;            // wave 0/1
  const int m    = lane & 15;
  const int quad = lane >> 4;
  const size_t blockRow = (size_t)blockIdx.x * 128;

  // staging assignment: thread t -> rows (t>>3)+16p, float4 col (t&7)
  const int srow = t >> 3;
  const int scol = (t & 7) * 4;
  const float* xg = x + blockRow * 512;

  // LDS read base addresses (one per row-frag)
  int rbase[4];
  #pragma unroll
  for (int f = 0; f < 4; ++f) rbase[f] = (w * 64 + f * 16 + m) * LSTRIDE + quad;

  const bf16x8* Bp = Bws + lane;

  f32x4 acc[4][4];
  #pragma unroll
  for (int f = 0; f < 4; ++f)
    #pragma unroll
    for (int ct = 0; ct < 4; ++ct) acc[f][ct] = (f32x4){0.f, 0.f, 0.f, 0.f};

  const float c3a = 5.f / 3.f,  c3b = 2.f / 3.f;
  const float c6a = 11.f / 6.f, c6b = 5.f / 6.f;
  const float c7a = 13.f / 7.f, c7b = 6.f / 7.f;

  // ---- prologue: stage chunk 0, preload B slots 0,1 (kt=0,1) ----
  {
    #pragma unroll
    for (int p = 0; p < 8; ++p) {
      float4 v = *(const float4*)(xg + (size_t)(srow + 16 * p) * 512 + scol);
      *(float4*)&xs[0][(srow + 16 * p) * LSTRIDE + scol] = v;
    }
  }
  __syncthreads();

  bf16x8 Bq[4][4];
  #pragma unroll
  for (int ct = 0; ct < 4; ++ct) {
    Bq[0][ct] = Bp[(size_t)(0 * 4 + ct) * 64];
    Bq[1][ct] = Bp[(size_t)(1 * 4 + ct) * 64];
  }

  for (int c = 0; c < 16; ++c) {
    const float* xr = xs[c & 1];
    float*       xw = xs[(c & 1) ^ 1];

    // issue next chunk's global loads early; hold in regs until chunk end
    float4 st[8];
    if (c < 15) {
      const float* gp = xg + (c + 1) * 32;
      #pragma unroll
      for (int p = 0; p < 8; ++p)
        st[p] = *(const float4*)(gp + (size_t)(srow + 16 * p) * 512 + scol);
    }

    // x prefetch for ktl=0
    float xv[2][4];
    #pragma unroll
    for (int f = 0; f < 4; ++f) xv[0][f] = xr[rbase[f]];

    #pragma unroll
    for (int ktl = 0; ktl < 8; ++ktl) {
      const int kt = c * 8 + ktl;

      // B prefetch distance 2 into rotating slot (compile-time index)
      {
        const int kp = (kt + 2) & 127;
        const bf16x8* bpk = Bp + (size_t)kp * 256;
        #pragma unroll
        for (int ct = 0; ct < 4; ++ct) Bq[(ktl + 2) & 3][ct] = bpk[ct * 64];
      }
      // x prefetch next ktl
      if (ktl < 7) {
        #pragma unroll
        for (int f = 0; f < 4; ++f)
          xv[(ktl + 1) & 1][f] = xr[rbase[f] + (ktl + 1) * 4];
      }

      // build 4 A-fragments (Legendre basis in fp32, pack to bf16)
      bf16x8 a[4];
      #pragma unroll
      for (int f = 0; f < 4; ++f) {
        float xn = fmaf(xv[ktl & 1][f], s, off);
        float p2 = fmaf(1.5f * xn, xn, -0.5f);
        float p3 = fmaf(c3a * xn, p2, -(c3b * xn));
        float p4 = fmaf(1.75f * xn, p3, -(0.75f * p2));
        float p5 = fmaf(1.8f * xn, p4, -(0.8f * p3));
        float p6 = fmaf(c6a * xn, p5, -(c6b * p4));
        float p7 = fmaf(c7a * xn, p6, -(c7b * p5));
        bf16x8 av;
        av[0] = (__bf16)1.0f; av[1] = (__bf16)xn; av[2] = (__bf16)p2; av[3] = (__bf16)p3;
        av[4] = (__bf16)p4;   av[5] = (__bf16)p5; av[6] = (__bf16)p6; av[7] = (__bf16)p7;
        a[f] = av;
      }

      #pragma unroll
      for (int f = 0; f < 4; ++f)
        #pragma unroll
        for (int ct = 0; ct < 4; ++ct)
          acc[f][ct] = __builtin_amdgcn_mfma_f32_16x16x32_bf16(a[f], Bq[ktl & 3][ct], acc[f][ct], 0, 0, 0);
    }

    // commit staged chunk to LDS, then barrier
    if (c < 15) {
      #pragma unroll
      for (int p = 0; p < 8; ++p)
        *(float4*)&xw[(srow + 16 * p) * LSTRIDE + scol] = st[p];
    }
    __syncthreads();
  }

  // ---- epilogue: bias + store. C/D layout: col = m, row = quad*4 + r ----
  float bv0 = bias[m], bv1 = bias[16 + m], bv2 = bias[32 + m], bv3 = bias[48 + m];
  #pragma unroll
  for (int f = 0; f < 4; ++f) {
    float* yp = y + (blockRow + w * 64 + f * 16 + quad * 4) * 64 + m;
    #pragma unroll
    for (int r = 0; r < 4; ++r) {
      float* ypr = yp + r * 64;
      ypr[0]  = acc[f][0][r] + bv0;
      ypr[16] = acc[f][1][r] + bv1;
      ypr[32] = acc[f][2][r] + bv2;
      ypr[48] = acc[f][3][r] + bv3;
    }
  }
}

// ---------------- fallback (no workspace for B): 16 rows/wave, direct coeff loads ----
__global__ __launch_bounds__(256) void k_main_simple(
    const float* __restrict__ x, const float* __restrict__ coeffs,
    const float* __restrict__ bias, const float* __restrict__ so, float* __restrict__ y)
{
  const float s = so[0], off = so[1];
  const int lane = threadIdx.x & 63;
  const int w    = threadIdx.x >> 6;
  const int m    = lane & 15;
  const int quad = lane >> 4;
  const int rowA = blockIdx.x * 64 + w * 16 + m;
  const float* xp = x + (size_t)rowA * 512 + quad;

  f32x4 acc0 = {0.f,0.f,0.f,0.f}, acc1 = acc0, acc2 = acc0, acc3 = acc0;
  const float c3a = 5.f/3.f, c3b = 2.f/3.f, c6a = 11.f/6.f, c6b = 5.f/6.f, c7a = 13.f/7.f, c7b = 6.f/7.f;

  for (int kt = 0; kt < 128; ++kt) {
    float xv = xp[kt * 4];
    int i = kt * 4 + quad;
    bf16x8 b[4];
    #pragma unroll
    for (int ct = 0; ct < 4; ++ct) {
      const float* cp = coeffs + ((size_t)(ct * 16 + m) * 512 + i) * 8;
      #pragma unroll
      for (int j = 0; j < 8; ++j) b[ct][j] = (__bf16)cp[j];
    }
    float xn = fmaf(xv, s, off);
    float p2 = fmaf(1.5f * xn, xn, -0.5f);
    float p3 = fmaf(c3a * xn, p2, -(c3b * xn));
    float p4 = fmaf(1.75f * xn, p3, -(0.75f * p2));
    float p5 = fmaf(1.8f * xn, p4, -(0.8f * p3));
    float p6 = fmaf(c6a * xn, p5, -(c6b * p4));
    float p7 = fmaf(c7a * xn, p6, -(c7b * p5));
    bf16x8 a;
    a[0] = (__bf16)1.0f; a[1] = (__bf16)xn; a[2] = (__bf16)p2; a[3] = (__bf16)p3;
    a[4] = (__bf16)p4;   a[5] = (__bf16)p5; a[6] = (__bf16)p6; a[7] = (__bf16)p7;
    acc0 = __builtin_amdgcn_mfma_f32_16x16x32_bf16(a, b[0], acc0, 0, 0, 0);
    acc1 = __builtin_amdgcn_mfma_f32_16x16x32_bf16(a, b[1], acc1, 0, 0, 0);
    acc2 = __builtin_amdgcn_mfma_f32_16x16x32_bf16(a, b[2], acc2, 0, 0, 0);
    acc3 = __builtin_amdgcn_mfma_f32_16x16x32_bf16(a, b[3], acc3, 0, 0, 0);
  }
  float b0v = bias[m], b1v = bias[16+m], b2v = bias[32+m], b3v = bias[48+m];
  float* yp = y + ((size_t)(blockIdx.x * 64 + w * 16 + quad * 4)) * 64 + m;
  #pragma unroll
  for (int r = 0; r < 4; ++r) {
    yp[r*64+ 0] = acc0[r] + b0v;
    yp[r*64+16] = acc1[r] + b1v;
    yp[r*64+32] = acc2[r] + b2v;
    yp[r*64+48] = acc3[r] + b3v;
  }
}

extern "C" void kernel_launch(void* const* d_in, const int* in_sizes, int n_in,
                              void* d_out, int out_size, void* d_ws, size_t ws_size,
                              hipStream_t stream)
{
  const float* x      = (const float*)d_in[0];
  const float* coeffs = (const float*)d_in[1];
  const float* bias   = (const float*)d_in[2];
  float* y = (float*)d_out;

  long nx = (long)in_sizes[0];        // 33,554,432
  int  N  = (int)(nx / 512);          // 65536 rows
  int  n4 = (int)(nx / 4);

  float*  so  = (float*)d_ws;
  float*  pmn = (float*)d_ws + 16;
  float*  pmx = pmn + 4096;
  bf16x8* Bws = (bf16x8*)((char*)d_ws + 65536);

  const int MMB = 2048;
  k_minmax_partial<<<MMB, 256, 0, stream>>>((const float4*)x, n4, pmn, pmx);
  k_minmax_final<<<1, 256, 0, stream>>>(pmn, pmx, MMB, so);

  bool pre = ws_size >= (size_t)(65536 + 4096 * 64 * 2 + 4096);
  if (pre) {
    k_prepB<<<128, 256, 0, stream>>>(coeffs, Bws);
    k_main<<<N / 128, 128, 0, stream>>>(x, Bws, bias, so, y);
  } else {
    k_main_simple<<<N / 64, 256, 0, stream>>>(x, coeffs, bias, so, y);
  }
}

// Round 4
// 252.294 us; speedup vs baseline: 1.2592x; 1.1397x over previous
//
#include <hip/hip_runtime.h>
#include <math.h>

// Legendre-KAN: y[n,o] = sum_{i,d} P_d(xn[n,i]) * coeffs[o,i,d] + bias[o]
// GEMM: A[65536 x 4096] (on-the-fly scaled-Legendre basis, bf16) * B[4096 x 64] (bf16).
// k_main: 4 waves/block, K-split 4; each wave = 64 rows x 1024 k (K-quarter).
// Wave-PRIVATE LDS x-tile (double-buffered, stride 20) -> NO barriers in the K-loop.
// Scaled recurrence S_n = x*S_{n-1} - c_n*S_{n-2}; per-degree g_n folded into B prep.
// LDS = 49152 B <= 64 KiB/workgroup cap (R3 crashed at 73728 B > cap).

typedef __bf16 bf16x8 __attribute__((ext_vector_type(8)));
typedef float f32x4 __attribute__((ext_vector_type(4)));

// ---------------- pass 1a: per-block min/max ----------------
__global__ __launch_bounds__(256) void k_minmax_partial(
    const float4* __restrict__ x4, int n4, float* __restrict__ pmn, float* __restrict__ pmx)
{
  float mn = 3.4e38f, mx = -3.4e38f;
  int stride = gridDim.x * 256;
  for (int i = blockIdx.x * 256 + threadIdx.x; i < n4; i += stride) {
    float4 v = x4[i];
    mn = fminf(mn, fminf(fminf(v.x, v.y), fminf(v.z, v.w)));
    mx = fmaxf(mx, fmaxf(fmaxf(v.x, v.y), fmaxf(v.z, v.w)));
  }
  #pragma unroll
  for (int off = 32; off > 0; off >>= 1) {
    mn = fminf(mn, __shfl_down(mn, off));
    mx = fmaxf(mx, __shfl_down(mx, off));
  }
  __shared__ float smn[4], smx[4];
  int w = threadIdx.x >> 6;
  if ((threadIdx.x & 63) == 0) { smn[w] = mn; smx[w] = mx; }
  __syncthreads();
  if (threadIdx.x == 0) {
    pmn[blockIdx.x] = fminf(fminf(smn[0], smn[1]), fminf(smn[2], smn[3]));
    pmx[blockIdx.x] = fmaxf(fmaxf(smx[0], smx[1]), fmaxf(smx[2], smx[3]));
  }
}

// ---------------- fused: prepB (blocks 0..127) + minmax final (block 128) ----------------
// Bws[(kt*4+ct)*64 + lane][j] = coeffs[o=ct*16+(lane&15)][i=kt*4+(lane>>4)][d=j] * g[j]
__global__ __launch_bounds__(256) void k_prep_final(
    const float* __restrict__ coeffs, bf16x8* __restrict__ Bws,
    const float* __restrict__ pmn, const float* __restrict__ pmx, int nb,
    float* __restrict__ so)
{
  if (blockIdx.x < 128) {
    int t = blockIdx.x * 256 + threadIdx.x;   // [0, 32768)
    int lane = t & 63;
    int tile = t >> 6;                        // kt*4 + ct
    int ct = tile & 3;
    int kt = tile >> 2;
    int i = kt * 4 + (lane >> 4);
    int o = ct * 16 + (lane & 15);
    const float4* cp = (const float4*)(coeffs + ((size_t)o * 512 + i) * 8);
    float4 c0 = cp[0], c1 = cp[1];
    // g_n: P_n = g_n * S_n;  g = {1,1,1.5,2.5,4.375,7.875,14.4375,26.8125}
    bf16x8 v;
    v[0] = (__bf16)(c0.x);
    v[1] = (__bf16)(c0.y);
    v[2] = (__bf16)(c0.z * 1.5f);
    v[3] = (__bf16)(c0.w * 2.5f);
    v[4] = (__bf16)(c1.x * 4.375f);
    v[5] = (__bf16)(c1.y * 7.875f);
    v[6] = (__bf16)(c1.z * 14.4375f);
    v[7] = (__bf16)(c1.w * 26.8125f);
    Bws[(size_t)(kt * 4 + ct) * 64 + lane] = v;
  } else {
    float mn = 3.4e38f, mx = -3.4e38f;
    for (int i = threadIdx.x; i < nb; i += 256) {
      mn = fminf(mn, pmn[i]);
      mx = fmaxf(mx, pmx[i]);
    }
    #pragma unroll
    for (int off = 32; off > 0; off >>= 1) {
      mn = fminf(mn, __shfl_down(mn, off));
      mx = fmaxf(mx, __shfl_down(mx, off));
    }
    __shared__ float smn[4], smx[4];
    int w = threadIdx.x >> 6;
    if ((threadIdx.x & 63) == 0) { smn[w] = mn; smx[w] = mx; }
    __syncthreads();
    if (threadIdx.x == 0) {
      mn = fminf(fminf(smn[0], smn[1]), fminf(smn[2], smn[3]));
      mx = fmaxf(fmaxf(smx[0], smx[1]), fmaxf(smx[2], smx[3]));
      float r = mx - mn;
      so[0] = 2.0f / r;               // scale
      so[1] = -2.0f * mn / r - 1.0f;  // offset:  xn = x*s + o
    }
  }
}

// ---------------- pass 2: fused basis + MFMA GEMM, barrier-free K-loop ----------------
// Block = 256 threads (4 waves). Wave w handles rows [blockRow, blockRow+64) x
// K-quarter w (global kt in [w*32, w*32+32)). Wave-private LDS tile:
//   xsw[buf][row*20 + i_local], buf in {0,1}, chunk = 16 i-cols (4 kt).
// Reads: addr = (16f+m)*20 + ktl*4 + quad -> bank 4(m%8)+quad (+const): 2-way only (free).
#define LSTW 20
__global__ __launch_bounds__(256, 3) void k_main(
    const float* __restrict__ x, const bf16x8* __restrict__ Bws,
    const float* __restrict__ bias, const float* __restrict__ so,
    float* __restrict__ y)
{
  __shared__ char smem[49152];   // 4 waves x 2 bufs x 64*20*4B = 40960 staging; 49152 for reduce

  const float s = so[0], off = so[1];
  const int t    = threadIdx.x;
  const int lane = t & 63;
  const int w    = t >> 6;        // K-quarter index
  const int m    = lane & 15;
  const int quad = lane >> 4;
  const size_t blockRow = (size_t)blockIdx.x * 64;

  float* xsw = (float*)(smem + w * (2 * 64 * LSTW * 4));   // wave-private [2][64*20]
  // staging: this lane stages row = lane of the block's 64 rows, this wave's i-range
  const float* xg = x + (blockRow + lane) * 512 + w * 128;

  int rb[4];
  #pragma unroll
  for (int f = 0; f < 4; ++f) rb[f] = (f * 16 + m) * LSTW + quad;

  // B fragment stream for this wave's K-quarter
  const bf16x8* Bp = Bws + (size_t)w * 32 * 256 + lane;

  f32x4 acc[4][4];
  #pragma unroll
  for (int f = 0; f < 4; ++f)
    #pragma unroll
    for (int ct = 0; ct < 4; ++ct) acc[f][ct] = (f32x4){0.f, 0.f, 0.f, 0.f};

  // scaled-recurrence constants c_n = b_n*g_{n-2}/g_n
  const float C2 = 0.33333334f, C3 = 0.26666668f, C4 = 0.25714287f;
  const float C5 = 0.25396827f, C6 = 0.25252524f, C7 = 0.25174826f;

  // ---- prologue: stage chunk 0 into buf 0; preload B slots 0,1 ----
  float4 st[4];
  #pragma unroll
  for (int p = 0; p < 4; ++p) st[p] = *(const float4*)(xg + p * 4);
  #pragma unroll
  for (int p = 0; p < 4; ++p) *(float4*)&xsw[lane * LSTW + p * 4] = st[p];

  bf16x8 Bq[4][4];
  #pragma unroll
  for (int ct = 0; ct < 4; ++ct) {
    Bq[0][ct] = Bp[ct * 64];
    Bq[1][ct] = Bp[256 + ct * 64];
  }

  for (int c = 0; c < 8; ++c) {            // 8 chunks x 4 kt = 32 kt (K-quarter)
    float* xr = xsw + (c & 1) * (64 * LSTW);

    // issue next chunk's global loads early (held in regs until chunk end)
    if (c < 7) {
      const float* gp = xg + (c + 1) * 16;
      #pragma unroll
      for (int p = 0; p < 4; ++p) st[p] = *(const float4*)(gp + p * 4);
    }

    float xv[2][4];
    #pragma unroll
    for (int f = 0; f < 4; ++f) xv[0][f] = xr[rb[f]];

    #pragma unroll
    for (int ktl = 0; ktl < 4; ++ktl) {
      const int l = c * 4 + ktl;           // local kt in [0,32)

      // B prefetch distance 2, 4-slot ring; slot = (ktl+2)&3 (c-independent)
      {
        const int kp = (l + 2) & 31;
        const bf16x8* bpk = Bp + (size_t)kp * 256;
        #pragma unroll
        for (int ct = 0; ct < 4; ++ct) Bq[(ktl + 2) & 3][ct] = bpk[ct * 64];
      }
      if (ktl < 3) {
        #pragma unroll
        for (int f = 0; f < 4; ++f)
          xv[(ktl + 1) & 1][f] = xr[rb[f] + (ktl + 1) * 4];
      }

      // scaled Legendre basis: S0=1, S1=xn, S_n = xn*S_{n-1} - c_n*S_{n-2}
      bf16x8 a[4];
      #pragma unroll
      for (int f = 0; f < 4; ++f) {
        float xn = fmaf(xv[ktl & 1][f], s, off);
        float s2 = fmaf(xn, xn, -C2);
        float s3 = (s2 - C3) * xn;
        float s4 = fmaf(xn, s3, -(C4 * s2));
        float s5 = fmaf(xn, s4, -(C5 * s3));
        float s6 = fmaf(xn, s5, -(C6 * s4));
        float s7 = fmaf(xn, s6, -(C7 * s5));
        bf16x8 av;
        av[0] = (__bf16)1.0f; av[1] = (__bf16)xn; av[2] = (__bf16)s2; av[3] = (__bf16)s3;
        av[4] = (__bf16)s4;   av[5] = (__bf16)s5; av[6] = (__bf16)s6; av[7] = (__bf16)s7;
        a[f] = av;
      }

      #pragma unroll
      for (int f = 0; f < 4; ++f)
        #pragma unroll
        for (int ct = 0; ct < 4; ++ct)
          acc[f][ct] = __builtin_amdgcn_mfma_f32_16x16x32_bf16(a[f], Bq[ktl & 3][ct], acc[f][ct], 0, 0, 0);
    }

    // commit next chunk to the other buffer (wave-private: no barrier; DS is
    // in-order per wave so next chunk's ds_reads see these writes)
    if (c < 7) {
      float* xw = xsw + ((c + 1) & 1) * (64 * LSTW);
      #pragma unroll
      for (int p = 0; p < 4; ++p) *(float4*)&xw[lane * LSTW + p * 4] = st[p];
    }
  }

  // ---- epilogue: reduce 4 K-quarters through LDS, then bias + store ----
  __syncthreads();                          // staging regions done; reuse as reduce buffer
  f32x4* red = (f32x4*)smem;                // 3 x 64*16 f32x4 = 48 KiB
  if (w > 0) {
    #pragma unroll
    for (int f = 0; f < 4; ++f)
      #pragma unroll
      for (int ct = 0; ct < 4; ++ct)
        red[(size_t)(w - 1) * 1024 + (f * 4 + ct) * 64 + lane] = acc[f][ct];
  }
  __syncthreads();
  if (w == 0) {
    #pragma unroll
    for (int f = 0; f < 4; ++f)
      #pragma unroll
      for (int ct = 0; ct < 4; ++ct) {
        f32x4 v = acc[f][ct];
        v += red[(f * 4 + ct) * 64 + lane];
        v += red[1024 + (f * 4 + ct) * 64 + lane];
        v += red[2048 + (f * 4 + ct) * 64 + lane];
        acc[f][ct] = v;
      }
    float bv0 = bias[m], bv1 = bias[16 + m], bv2 = bias[32 + m], bv3 = bias[48 + m];
    // C/D layout: col = m, row = quad*4 + r
    #pragma unroll
    for (int f = 0; f < 4; ++f) {
      float* yp = y + (blockRow + f * 16 + quad * 4) * 64 + m;
      #pragma unroll
      for (int r = 0; r < 4; ++r) {
        float* ypr = yp + r * 64;
        ypr[0]  = acc[f][0][r] + bv0;
        ypr[16] = acc[f][1][r] + bv1;
        ypr[32] = acc[f][2][r] + bv2;
        ypr[48] = acc[f][3][r] + bv3;
      }
    }
  }
}

// ---------------- fallback (no workspace): 16 rows/wave, direct coeff loads ----
__global__ __launch_bounds__(256) void k_main_simple(
    const float* __restrict__ x, const float* __restrict__ coeffs,
    const float* __restrict__ bias, const float* __restrict__ so, float* __restrict__ y)
{
  const float s = so[0], off = so[1];
  const int lane = threadIdx.x & 63;
  const int w    = threadIdx.x >> 6;
  const int m    = lane & 15;
  const int quad = lane >> 4;
  const int rowA = blockIdx.x * 64 + w * 16 + m;
  const float* xp = x + (size_t)rowA * 512 + quad;

  f32x4 acc0 = {0.f,0.f,0.f,0.f}, acc1 = acc0, acc2 = acc0, acc3 = acc0;
  const float c3a = 5.f/3.f, c3b = 2.f/3.f, c6a = 11.f/6.f, c6b = 5.f/6.f, c7a = 13.f/7.f, c7b = 6.f/7.f;

  for (int kt = 0; kt < 128; ++kt) {
    float xv = xp[kt * 4];
    int i = kt * 4 + quad;
    bf16x8 b[4];
    #pragma unroll
    for (int ct = 0; ct < 4; ++ct) {
      const float* cp = coeffs + ((size_t)(ct * 16 + m) * 512 + i) * 8;
      #pragma unroll
      for (int j = 0; j < 8; ++j) b[ct][j] = (__bf16)cp[j];
    }
    float xn = fmaf(xv, s, off);
    float p2 = fmaf(1.5f * xn, xn, -0.5f);
    float p3 = fmaf(c3a * xn, p2, -(c3b * xn));
    float p4 = fmaf(1.75f * xn, p3, -(0.75f * p2));
    float p5 = fmaf(1.8f * xn, p4, -(0.8f * p3));
    float p6 = fmaf(c6a * xn, p5, -(c6b * p4));
    float p7 = fmaf(c7a * xn, p6, -(c7b * p5));
    bf16x8 a;
    a[0] = (__bf16)1.0f; a[1] = (__bf16)xn; a[2] = (__bf16)p2; a[3] = (__bf16)p3;
    a[4] = (__bf16)p4;   a[5] = (__bf16)p5; a[6] = (__bf16)p6; a[7] = (__bf16)p7;
    acc0 = __builtin_amdgcn_mfma_f32_16x16x32_bf16(a, b[0], acc0, 0, 0, 0);
    acc1 = __builtin_amdgcn_mfma_f32_16x16x32_bf16(a, b[1], acc1, 0, 0, 0);
    acc2 = __builtin_amdgcn_mfma_f32_16x16x32_bf16(a, b[2], acc2, 0, 0, 0);
    acc3 = __builtin_amdgcn_mfma_f32_16x16x32_bf16(a, b[3], acc3, 0, 0, 0);
  }
  float b0v = bias[m], b1v = bias[16+m], b2v = bias[32+m], b3v = bias[48+m];
  float* yp = y + ((size_t)(blockIdx.x * 64 + w * 16 + quad * 4)) * 64 + m;
  #pragma unroll
  for (int r = 0; r < 4; ++r) {
    yp[r*64+ 0] = acc0[r] + b0v;
    yp[r*64+16] = acc1[r] + b1v;
    yp[r*64+32] = acc2[r] + b2v;
    yp[r*64+48] = acc3[r] + b3v;
  }
}

extern "C" void kernel_launch(void* const* d_in, const int* in_sizes, int n_in,
                              void* d_out, int out_size, void* d_ws, size_t ws_size,
                              hipStream_t stream)
{
  const float* x      = (const float*)d_in[0];
  const float* coeffs = (const float*)d_in[1];
  const float* bias   = (const float*)d_in[2];
  float* y = (float*)d_out;

  long nx = (long)in_sizes[0];        // 33,554,432
  int  N  = (int)(nx / 512);          // 65536 rows
  int  n4 = (int)(nx / 4);

  float*  so  = (float*)d_ws;
  float*  pmn = (float*)d_ws + 16;
  float*  pmx = pmn + 4096;
  bf16x8* Bws = (bf16x8*)((char*)d_ws + 65536);

  const int MMB = 2048;
  k_minmax_partial<<<MMB, 256, 0, stream>>>((const float4*)x, n4, pmn, pmx);

  bool pre = ws_size >= (size_t)(65536 + 4096 * 64 * 2 + 4096);
  k_prep_final<<<129, 256, 0, stream>>>(coeffs, Bws, pmn, pmx, MMB, so);
  if (pre) {
    k_main<<<N / 64, 256, 0, stream>>>(x, Bws, bias, so, y);
  } else {
    k_main_simple<<<N / 64, 256, 0, stream>>>(x, coeffs, bias, so, y);
  }
}